// Round 10
// baseline (412.325 us; speedup 1.0000x reference)
//
#include <hip/hip_runtime.h>
#include <hip/hip_fp8.h>
#include <stdint.h>

#define TT 500
#define HT 250            // steps per direction
#define NB 32
#define RS 1024
#define CD 5120
#define LT 400
#define NC 396
#define NEGF (-1e30f)
#define L2E 1.4426950408889634f
#define LN2f 0.6931471805599453f

#define NRING 5
#define SLAB_B_F32 20480
#define SLAB_B_F8  5120
#define SMEM_MAX (NRING*SLAB_B_F32 + 2*RS*4)   // 110592 B (fp32 fallback)
#define SMEM_F8  (NRING*SLAB_B_F8  + 2*RS*4)   // 33792 B

// fp8 image: per slab s=t*32+b, 5120 B: planeA = uint4 per group g (f0..f15)
// at byte 16g; planeB = uint per group (f16..f19) at 4096+4g.
#define IMG_BYTES 81920000ull                  // 500*32*5120

// float workspace layout (indices into wsf)
#define WS_AT 0
#define WS_BT (NB*RS)
#define WS_AC (2*NB*RS)
#define WS_BC (2*NB*RS + NB*NC)
#define WSF_FLOATS (2*NB*RS + 2*NB*NC)

#define PHASE_SYNC_F8() do {                               \
    __builtin_amdgcn_sched_barrier(0);                     \
    asm volatile("s_waitcnt vmcnt(4) lgkmcnt(0)");         \
    __builtin_amdgcn_s_barrier();                          \
    __builtin_amdgcn_sched_barrier(0);                     \
} while (0)
#define PHASE_SYNC_F32() do {                              \
    __builtin_amdgcn_sched_barrier(0);                     \
    asm volatile("s_waitcnt vmcnt(10) lgkmcnt(0)");        \
    __builtin_amdgcn_s_barrier();                          \
    __builtin_amdgcn_sched_barrier(0);                     \
} while (0)

#define ROT5(x) do { x = (x == 4) ? 0 : x + 1; } while (0)

__device__ __forceinline__ float f8dec(unsigned v) {
    __hip_fp8_e4m3 t; t.__x = (__hip_fp8_storage_t)(v & 0xffu);
    return (float)t;
}

__device__ __forceinline__ float lse5(float t0,float t1,float t2,float t3,float t4){
    float mx = fmaxf(fmaxf(fmaxf(t0,t1),t2), fmaxf(t3,t4));
    float e = exp2f(t0-mx)+exp2f(t1-mx)+exp2f(t2-mx)+exp2f(t3-mx)+exp2f(t4-mx);
    return mx + log2f(e);
}

// fwd: states 4*tid..4*tid+3 share parent quad {tid, tid+256, tid+512, tid+768}
__device__ __forceinline__ void compute4(const float (&f)[20], float (&ao)[4],
                                         float p0, float p1, float p2, float p3) {
    ao[0] = lse5(fmaf(f[0],L2E,ao[0]),  fmaf(f[1],L2E,p0),  fmaf(f[2],L2E,p1),
                 fmaf(f[3],L2E,p2),     fmaf(f[4],L2E,p3));
    ao[1] = lse5(fmaf(f[5],L2E,ao[1]),  fmaf(f[6],L2E,p0),  fmaf(f[7],L2E,p1),
                 fmaf(f[8],L2E,p2),     fmaf(f[9],L2E,p3));
    ao[2] = lse5(fmaf(f[10],L2E,ao[2]), fmaf(f[11],L2E,p0), fmaf(f[12],L2E,p1),
                 fmaf(f[13],L2E,p2),    fmaf(f[14],L2E,p3));
    ao[3] = lse5(fmaf(f[15],L2E,ao[3]), fmaf(f[16],L2E,p0), fmaf(f[17],L2E,p1),
                 fmaf(f[18],L2E,p2),    fmaf(f[19],L2E,p3));
}

// bwd: own states tid+256j; children 4*tid..4*tid+3 (bc quad)
__device__ __forceinline__ void computeB(const float (&f)[20], const float (&st)[4],
                                         float (&bo)[4], float4 bc) {
    bo[0] = lse5(fmaf(st[0],L2E,bo[0]), fmaf(f[1],L2E,bc.x),  fmaf(f[6],L2E,bc.y),
                 fmaf(f[11],L2E,bc.z),  fmaf(f[16],L2E,bc.w));
    bo[1] = lse5(fmaf(st[1],L2E,bo[1]), fmaf(f[2],L2E,bc.x),  fmaf(f[7],L2E,bc.y),
                 fmaf(f[12],L2E,bc.z),  fmaf(f[17],L2E,bc.w));
    bo[2] = lse5(fmaf(st[2],L2E,bo[2]), fmaf(f[3],L2E,bc.x),  fmaf(f[8],L2E,bc.y),
                 fmaf(f[13],L2E,bc.z),  fmaf(f[18],L2E,bc.w));
    bo[3] = lse5(fmaf(st[3],L2E,bo[3]), fmaf(f[4],L2E,bc.x),  fmaf(f[9],L2E,bc.y),
                 fmaf(f[14],L2E,bc.z),  fmaf(f[19],L2E,bc.w));
}

// ===================== banded CTC (one wave, depth-5 register prefetch) =====
__device__ __forceinline__ void ldc(const float* __restrict__ p,
                                    const int (&so)[7], const int (&mo)[7],
                                    float (&S)[7], float (&V)[7]) {
#pragma unroll
    for (int k = 0; k < 7; ++k) { S[k] = p[so[k]]; V[k] = p[mo[k]]; }
}

__device__ __forceinline__ void cstep(const float (&S)[7], const float (&V)[7],
                                      float (&ac)[7], int lane) {
    float prev = __shfl_up(ac[6], 1, 64);
    float nw[7];
#pragma unroll
    for (int k = 0; k < 7; ++k) {
        float left = k ? ac[k-1] : prev;
        float x = fmaf(S[k], L2E, ac[k]);
        float y = fmaf(V[k], L2E, left);
        if (k == 0) y = (lane == 0) ? NEGF : y;
        float m2 = fmaxf(x, y);
        float d  = fminf(x, y) - m2;
        nw[k] = m2 + log2f(1.0f + exp2f(d));
    }
#pragma unroll
    for (int k = 0; k < 7; ++k) ac[k] = nw[k];
}

__device__ __forceinline__ void cstep_b(const float (&S)[7], const float (&V)[7],
                                        float (&ac)[7], int lane) {
    float nxt = __shfl_down(ac[0], 1, 64);
    float nw[7];
#pragma unroll
    for (int k = 0; k < 7; ++k) {
        int gi = 7*lane + k;
        float bn = (k < 6) ? ac[k+1] : nxt;
        float x = fmaf(S[k], L2E, ac[k]);
        float y = fmaf(V[k], L2E, bn);
        y = (gi < NC-1) ? y : NEGF;
        float m2 = fmaxf(x, y);
        float d  = fminf(x, y) - m2;
        float r  = m2 + log2f(1.0f + exp2f(d));
        nw[k] = (gi < NC) ? r : NEGF;
    }
#pragma unroll
    for (int k = 0; k < 7; ++k) ac[k] = nw[k];
}

__device__ void build_tloc(const int* __restrict__ targets, int b, int lane, int (&tloc)[12]) {
#pragma unroll
    for (int j = 0; j < 12; ++j) {
        int gi = 7*lane - 1 + j;
        gi = gi < 0 ? 0 : (gi > LT-1 ? LT-1 : gi);
        int v = targets[b*LT + gi] - 1;
        tloc[j] = v < 0 ? 0 : v;
    }
}

__device__ void ctc_fwd(const float* __restrict__ scores, const int* __restrict__ targets,
                        float* __restrict__ wsf, int b, int lane) {
    int tloc[12]; build_tloc(targets, b, lane, tloc);
    int so[7], mo[7];
#pragma unroll
    for (int k = 0; k < 7; ++k) {
        int gi = 7*lane + k;
        if (gi < NC) {
            int K = tloc[k+1];
            K = K*4 + tloc[k+2]; K = K*4 + tloc[k+3];
            K = K*4 + tloc[k+4]; K = K*4 + tloc[k+5];
            so[k] = K*5;
            mo[k] = (gi >= 1) ? (so[k] + tloc[k] + 1) : 0;
        } else { so[k] = 0; mo[k] = 0; }
    }
    float ac[7];
#pragma unroll
    for (int k = 0; k < 7; ++k) ac[k] = (7*lane + k == 0) ? 0.f : NEGF;

    const size_t STP = (size_t)NB*CD;
    const float* qb = scores + (size_t)b*CD;
    float S[5][7], V[5][7];
#pragma unroll
    for (int j = 0; j < 5; ++j) ldc(qb + (size_t)j*STP, so, mo, S[j], V[j]);
    for (int t = 0; t < HT; t += 5) {
#pragma unroll
        for (int j = 0; j < 5; ++j) {
            cstep(S[j], V[j], ac, lane);
            int ts = t + 5 + j;
            if (ts < HT) ldc(qb + (size_t)ts*STP, so, mo, S[j], V[j]);
        }
    }
#pragma unroll
    for (int k = 0; k < 7; ++k) {
        int gi = 7*lane + k;
        if (gi < NC) wsf[WS_AC + b*NC + gi] = ac[k];
    }
}

__device__ void ctc_bwd(const float* __restrict__ scores, const int* __restrict__ targets,
                        const int* __restrict__ tlens, float* __restrict__ wsf, int b, int lane) {
    int tloc[12]; build_tloc(targets, b, lane, tloc);
    int so[7], vo[7];
#pragma unroll
    for (int k = 0; k < 7; ++k) {
        int gi = 7*lane + k;
        if (gi < NC) {
            int K = tloc[k+1];
            K = K*4 + tloc[k+2]; K = K*4 + tloc[k+3];
            K = K*4 + tloc[k+4]; K = K*4 + tloc[k+5];
            so[k] = K*5;
            if (gi < NC-1) {
                int K2 = tloc[k+2];
                K2 = K2*4 + tloc[k+3]; K2 = K2*4 + tloc[k+4];
                K2 = K2*4 + tloc[k+5]; K2 = K2*4 + tloc[k+6];
                vo[k] = K2*5 + tloc[k+1] + 1;
            } else vo[k] = 0;
        } else { so[k] = 0; vo[k] = 0; }
    }
    int tl = tlens[b];
    float ac[7];
#pragma unroll
    for (int k = 0; k < 7; ++k) ac[k] = (7*lane + k == tl-5) ? 0.f : NEGF;

    const size_t STP = (size_t)NB*CD;
    const float* qb = scores + (size_t)b*CD;
    float S[5][7], V[5][7];
#pragma unroll
    for (int j = 0; j < 5; ++j) ldc(qb + (size_t)(TT-1-j)*STP, so, vo, S[j], V[j]);
    for (int p = 0; p < HT; p += 5) {
#pragma unroll
        for (int j = 0; j < 5; ++j) {
            cstep_b(S[j], V[j], ac, lane);
            int ps = p + 5 + j;
            if (ps < HT) ldc(qb + (size_t)(TT-1-ps)*STP, so, vo, S[j], V[j]);
        }
    }
#pragma unroll
    for (int k = 0; k < 7; ++k) {
        int gi = 7*lane + k;
        if (gi < NC) wsf[WS_BC + b*NC + gi] = ac[k];
    }
}

// ============ kernel A: CTC (blocks 0..63) + fp32->fp8 convert (rest) ========
extern "C" __global__ void __launch_bounds__(256, 1)
conv_ctc(const float* __restrict__ scores, unsigned char* __restrict__ img,
         const int* __restrict__ targets, const int* __restrict__ tlens,
         float* __restrict__ wsf, int useF8)
{
    const int tid = threadIdx.x, blk = blockIdx.x;
    if (blk < 2*NB) {
        if (tid >= 64) return;
        if (blk < NB) ctc_fwd(scores, targets, wsf, blk, tid);
        else          ctc_bwd(scores, targets, tlens, wsf, blk - NB, tid);
        return;
    }
    if (!useF8) return;
    const size_t s = blk - 2*NB;
    const float4* p4 = (const float4*)(scores + s*(size_t)CD + 20*tid);
    float4 v0 = p4[0], v1 = p4[1], v2 = p4[2], v3 = p4[3], v4 = p4[4];
    float f[20] = {v0.x,v0.y,v0.z,v0.w, v1.x,v1.y,v1.z,v1.w,
                   v2.x,v2.y,v2.z,v2.w, v3.x,v3.y,v3.z,v3.w,
                   v4.x,v4.y,v4.z,v4.w};
    unsigned q[5];
#pragma unroll
    for (int i = 0; i < 5; ++i) {
        unsigned b0, b1, b2, b3;
        { __hip_fp8_e4m3 t(f[4*i+0]); b0 = t.__x; }
        { __hip_fp8_e4m3 t(f[4*i+1]); b1 = t.__x; }
        { __hip_fp8_e4m3 t(f[4*i+2]); b2 = t.__x; }
        { __hip_fp8_e4m3 t(f[4*i+3]); b3 = t.__x; }
        q[i] = b0 | (b1 << 8) | (b2 << 16) | (b3 << 24);
    }
    unsigned char* out = img + s*(size_t)SLAB_B_F8;
    *(uint4*)(out + 16*tid) = make_uint4(q[0], q[1], q[2], q[3]);
    *(unsigned*)(out + 4096 + 4*tid) = q[4];
}

// ===================== kernel B: trellis (templated: fp8 vs fp32) ===========
template<bool F8>
__device__ void trellis(const float* __restrict__ scores,
                        const unsigned char* __restrict__ img,
                        float* __restrict__ wsf, int c, int tid, char* sm)
{
    constexpr int SLAB_B = F8 ? SLAB_B_F8 : SLAB_B_F32;
    const bool is_fwd = c < NB;
    const int b = c & (NB-1);
    const int w = tid >> 6, lane = tid & 63;
    float* A0 = (float*)(sm + NRING*SLAB_B);
    float* A1 = A0 + RS;

    *(float4*)&A0[4*tid] = make_float4(0.f,0.f,0.f,0.f);

    auto stage = [&](int t, int slot) {
        if constexpr (F8) {
            const unsigned char* src = img + ((size_t)t*NB + b)*(size_t)SLAB_B_F8 + w*1280;
            char* dst = sm + slot*SLAB_B + w*1280;
            __builtin_amdgcn_global_load_lds(
                (const __attribute__((address_space(1))) void*)(src + lane*16),
                (__attribute__((address_space(3))) void*)(dst), 16, 0, 0);
            __builtin_amdgcn_global_load_lds(
                (const __attribute__((address_space(1))) void*)(src + 1024 + lane*4),
                (__attribute__((address_space(3))) void*)(dst + 1024), 4, 0, 0);
        } else {
            const char* src = (const char*)(scores + ((size_t)t*NB + b)*(size_t)CD) + w*5120;
            char* dst = sm + slot*SLAB_B + w*5120;
#pragma unroll
            for (int m = 0; m < 5; ++m)
                __builtin_amdgcn_global_load_lds(
                    (const __attribute__((address_space(1))) void*)(src + m*1024 + lane*16),
                    (__attribute__((address_space(3))) void*)(dst + m*1024), 16, 0, 0);
        }
    };

    auto rd20 = [&](int slot, float (&f)[20]) {
        const char* sl = sm + slot*SLAB_B;
        if constexpr (F8) {
            uint4 ua = *(const uint4*)(sl + 16*tid);
            unsigned ub = *(const unsigned*)(sl + 4096 + 4*tid);
            unsigned q[5] = {ua.x, ua.y, ua.z, ua.w, ub};
#pragma unroll
            for (int i = 0; i < 5; ++i) {
                f[4*i+0] = f8dec(q[i]);
                f[4*i+1] = f8dec(q[i] >> 8);
                f[4*i+2] = f8dec(q[i] >> 16);
                f[4*i+3] = f8dec(q[i] >> 24);
            }
        } else {
            const float4* q4 = (const float4*)(sl + 80*tid);
            float4 r0=q4[0], r1=q4[1], r2=q4[2], r3=q4[3], r4=q4[4];
            f[0]=r0.x; f[1]=r0.y; f[2]=r0.z; f[3]=r0.w;
            f[4]=r1.x; f[5]=r1.y; f[6]=r1.z; f[7]=r1.w;
            f[8]=r2.x; f[9]=r2.y; f[10]=r2.z; f[11]=r2.w;
            f[12]=r3.x; f[13]=r3.y; f[14]=r3.z; f[15]=r3.w;
            f[16]=r4.x; f[17]=r4.y; f[18]=r4.z; f[19]=r4.w;
        }
    };

    auto rdst = [&](int slot, float (&st)[4]) {
        const char* sl = sm + slot*SLAB_B;
        if constexpr (F8) {
            const int sel5 = 5*(tid & 3);
#pragma unroll
            for (int j = 0; j < 4; ++j) {
                int g = (tid >> 2) + 64*j;
                st[j] = f8dec(*(const unsigned char*)(sl + 16*g + sel5));
            }
        } else {
            const float* slf = (const float*)sl;
            st[0] = slf[5*tid];        st[1] = slf[5*tid + 1280];
            st[2] = slf[5*tid + 2560]; st[3] = slf[5*tid + 3840];
        }
    };

#pragma unroll
    for (int p = 0; p < 4; ++p)
        stage(is_fwd ? p : (TT-1-p), p);
    __syncthreads();

    float Ma[20], Mb[20]; float sta[4], stb[4];
    float ao[4] = {0.f,0.f,0.f,0.f};
    rd20(0, Ma);
    if (!is_fwd) rdst(0, sta);

    int s_rd = 1, s_st = 4;

    for (int k = 0; k < HT; k += 2) {
        if constexpr (F8) PHASE_SYNC_F8(); else PHASE_SYNC_F32();
        {
            int ts = k + 4; if (ts > HT-1) ts = HT-1;
            stage(is_fwd ? ts : (TT-1-ts), s_st);
        }
        if (is_fwd) {
            float p0 = A0[tid], p1 = A0[tid+256], p2 = A0[tid+512], p3 = A0[tid+768];
            rd20(s_rd, Mb);
            compute4(Ma, ao, p0, p1, p2, p3);
            *(float4*)&A1[4*tid] = make_float4(ao[0],ao[1],ao[2],ao[3]);
        } else {
            float4 bc = *(const float4*)&A0[4*tid];
            rd20(s_rd, Mb);
            rdst(s_rd, stb);
            computeB(Ma, sta, ao, bc);
            A1[tid] = ao[0]; A1[tid+256] = ao[1]; A1[tid+512] = ao[2]; A1[tid+768] = ao[3];
        }
        ROT5(s_rd); ROT5(s_st);

        if constexpr (F8) PHASE_SYNC_F8(); else PHASE_SYNC_F32();
        {
            int ts = k + 5; if (ts > HT-1) ts = HT-1;
            stage(is_fwd ? ts : (TT-1-ts), s_st);
        }
        if (is_fwd) {
            float p0 = A1[tid], p1 = A1[tid+256], p2 = A1[tid+512], p3 = A1[tid+768];
            rd20(s_rd, Ma);
            compute4(Mb, ao, p0, p1, p2, p3);
            *(float4*)&A0[4*tid] = make_float4(ao[0],ao[1],ao[2],ao[3]);
        } else {
            float4 bc = *(const float4*)&A1[4*tid];
            rd20(s_rd, Ma);
            rdst(s_rd, sta);
            computeB(Mb, stb, ao, bc);
            A0[tid] = ao[0]; A0[tid+256] = ao[1]; A0[tid+512] = ao[2]; A0[tid+768] = ao[3];
        }
        ROT5(s_rd); ROT5(s_st);
    }

    if (is_fwd) {
        *(float4*)&wsf[WS_AT + b*RS + 4*tid] = make_float4(ao[0],ao[1],ao[2],ao[3]);
    } else {
        wsf[WS_BT + b*RS + tid]       = ao[0];
        wsf[WS_BT + b*RS + tid + 256] = ao[1];
        wsf[WS_BT + b*RS + tid + 512] = ao[2];
        wsf[WS_BT + b*RS + tid + 768] = ao[3];
    }
}

extern "C" __global__ void __launch_bounds__(256, 1)
trellis_k(const float* __restrict__ scores, const unsigned char* __restrict__ img,
          float* __restrict__ wsf, int useF8)
{
    extern __shared__ float smf[];
    char* sm = (char*)smf;
    if (useF8) trellis<true>(scores, img, wsf, blockIdx.x, threadIdx.x, sm);
    else       trellis<false>(scores, img, wsf, blockIdx.x, threadIdx.x, sm);
}

// ===================== kernel C: combine =====================
extern "C" __global__ void __launch_bounds__(256, 1)
ctc_crf_combine(const float* __restrict__ wsf, const int* __restrict__ tlens,
                float* __restrict__ out)
{
    const int b = blockIdx.x, tid = threadIdx.x, lane = tid & 63, w = tid >> 6;
    __shared__ float r1[4], r2[4];

    float4 a4 = *(const float4*)&wsf[WS_AT + b*RS + 4*tid];
    float4 b4 = *(const float4*)&wsf[WS_BT + b*RS + 4*tid];
    float v0 = a4.x+b4.x, v1 = a4.y+b4.y, v2 = a4.z+b4.z, v3 = a4.w+b4.w;
    float m = fmaxf(fmaxf(v0,v1), fmaxf(v2,v3));
#pragma unroll
    for (int o = 32; o >= 1; o >>= 1) m = fmaxf(m, __shfl_xor(m, o, 64));
    if (lane == 0) r1[w] = m;
    __syncthreads();
    float g = fmaxf(fmaxf(r1[0],r1[1]), fmaxf(r1[2],r1[3]));
    float e = exp2f(v0-g)+exp2f(v1-g)+exp2f(v2-g)+exp2f(v3-g);
#pragma unroll
    for (int o = 32; o >= 1; o >>= 1) e += __shfl_xor(e, o, 64);
    if (lane == 0) r2[w] = e;
    __syncthreads();
    float zfull = g + log2f(r2[0]+r2[1]+r2[2]+r2[3]);
    __syncthreads();

    float c0 = (tid < NC)     ? wsf[WS_AC + b*NC + tid]       + wsf[WS_BC + b*NC + tid]       : NEGF;
    float c1 = (tid+256 < NC) ? wsf[WS_AC + b*NC + tid + 256] + wsf[WS_BC + b*NC + tid + 256] : NEGF;
    float mc = fmaxf(c0, c1);
#pragma unroll
    for (int o = 32; o >= 1; o >>= 1) mc = fmaxf(mc, __shfl_xor(mc, o, 64));
    if (lane == 0) r1[w] = mc;
    __syncthreads();
    float gc = fmaxf(fmaxf(r1[0],r1[1]), fmaxf(r1[2],r1[3]));
    float ec = exp2f(c0-gc)+exp2f(c1-gc);
#pragma unroll
    for (int o = 32; o >= 1; o >>= 1) ec += __shfl_xor(ec, o, 64);
    if (lane == 0) r2[w] = ec;
    __syncthreads();
    if (tid == 0) {
        float zctc = gc + log2f(r2[0]+r2[1]+r2[2]+r2[3]);
        int tl = tlens[b];
        float loss_b = LN2f * (zfull - zctc) / (float)tl;
        atomicAdd(out, loss_b / (float)NB);
    }
}

extern "C" void kernel_launch(void* const* d_in, const int* in_sizes, int n_in,
                              void* d_out, int out_size, void* d_ws, size_t ws_size,
                              hipStream_t stream) {
    const float* scores  = (const float*)d_in[0];
    const int*   targets = (const int*)d_in[1];
    const int*   tlens   = (const int*)d_in[2];
    float* out = (float*)d_out;

    const size_t need = IMG_BYTES + (size_t)WSF_FLOATS*4 + 1024;
    const int useF8 = (ws_size >= need) ? 1 : 0;
    unsigned char* img = (unsigned char*)d_ws;
    float* wsf = useF8 ? (float*)((char*)d_ws + IMG_BYTES) : (float*)d_ws;

    hipFuncSetAttribute((const void*)trellis_k,
                        hipFuncAttributeMaxDynamicSharedMemorySize, SMEM_MAX);
    hipMemsetAsync(out, 0, sizeof(float), stream);
    conv_ctc<<<2*NB + TT*NB, 256, 0, stream>>>(scores, img, targets, tlens, wsf, useF8);
    trellis_k<<<2*NB, 256, useF8 ? SMEM_F8 : SMEM_MAX, stream>>>(scores, img, wsf, useF8);
    ctc_crf_combine<<<NB, 256, 0, stream>>>(wsf, tlens, out);
}